// Round 19
// baseline (1129.666 us; speedup 1.0000x reference)
//
#include <hip/hip_runtime.h>
#include <stdint.h>

#define GAS __attribute__((address_space(1)))
#define LAS __attribute__((address_space(3)))

typedef __attribute__((ext_vector_type(4))) float f32x4;
typedef unsigned char uchar;
typedef long long i64f;

static constexpr int NB = 8192;    // batch
static constexpr int DD = 768;     // model dim (K)
static constexpr int FF = 32768;   // latent dim (N)
static constexpr int TK = 32;      // top-k
static constexpr int RUNC = 64;    // refined candidate cap
static constexpr int SLOT = 8;     // survivor slots per (row, 128-col segment)
static constexpr int NSEG = FF / 128;  // 256 segments per row
static constexpr int SORTN = 1024; // select2 sort size
static constexpr int NS2 = 256;    // partial-sum slots for mean(W^2)
static constexpr int NKT = DD / 32;    // 24 K-tiles of 32
static constexpr int PQ8 = 128 * 32;   // panel BYTES per K-tile (4 KB, 128-row tiles)
// W scaled by 64 before e4m3: w*64 ~ N(0,0.49) in e4m3 NORMAL range (r13/r14 lesson)
static constexpr float WSC = 64.0f;
static constexpr float WSCI = 1.0f / 64.0f;

__device__ __forceinline__ ushort f2bf(float f) {
    unsigned x = __float_as_uint(f);
    unsigned r = (x + 0x7FFFu + ((x >> 16) & 1u)) >> 16;
    return (ushort)r;
}
__device__ __forceinline__ ushort sortkey(ushort u) {
    return (u & 0x8000u) ? (ushort)(u ^ 0xFFFFu) : (ushort)(u | 0x8000u);
}
__device__ __forceinline__ float bf2f(ushort u) {
    return __uint_as_float(((unsigned)u) << 16);
}
__device__ __forceinline__ float e4m3f(uchar b) {
    int e = (b >> 3) & 0xF, m = b & 7;
    float v = (e == 0) ? ldexpf((float)m, -9) : ldexpf((float)(8 + m), e - 10);
    return (b & 0x80) ? -v : v;
}
__device__ __forceinline__ uchar f2e4m3(float v) {
    return (uchar)(__builtin_amdgcn_cvt_pk_fp8_f32(v, v, 0, false) & 0xFF);
}
__device__ __forceinline__ void gload_lds16(const void* g, void* l) {
    __builtin_amdgcn_global_load_lds((const GAS unsigned int*)g,
                                     (LAS unsigned int*)l, 16, 0, 0);
}
// panel BYTE offset: [vtile=v>>7][kt=d>>5][v&127][d&31]  (row-major 32-B rows)
__device__ __forceinline__ size_t pan_off8(int v, int d) {
    return ((size_t)(v >> 7) * NKT + (d >> 5)) * PQ8 + ((v & 127) << 5) + (d & 31);
}

// ---------------- prep: A panels = e4m3(x - pre_bias), packed ----------------
__global__ __launch_bounds__(256) void prep_x_k(const float* __restrict__ x,
                                                const float* __restrict__ pb,
                                                uchar* __restrict__ Ap) {
    const int n4 = NB * DD / 4;
    for (int i = blockIdx.x * 256 + threadIdx.x; i < n4; i += gridDim.x * 256) {
        int b = i / (DD / 4), dq = (i % (DD / 4)) * 4;
        float4 v = ((const float4*)x)[i];
        float4 p = ((const float4*)pb)[i % (DD / 4)];
        int w = __builtin_amdgcn_cvt_pk_fp8_f32(v.x - p.x, v.y - p.y, 0, false);
        w = __builtin_amdgcn_cvt_pk_fp8_f32(v.z - p.z, v.w - p.w, w, true);
        *(unsigned*)(Ap + pan_off8(b, dq)) = (unsigned)w;
    }
}

// ------------- prep: W_enc [D,F] -> B panels (e4m3, x64 scaled) + Wt32 [F,D] + sum(W^2) -------------
__global__ __launch_bounds__(256) void prep_w_k(const float* __restrict__ W,
                                                uchar* __restrict__ Bp,
                                                float* __restrict__ Wt32,
                                                float* __restrict__ s2part) {
    __shared__ float tile[32][33];
    int f0 = blockIdx.x * 32, d0 = blockIdx.y * 32;
    int tx = threadIdx.x & 31, ty = threadIdx.x >> 5;  // ty 0..7
    float ss = 0.f;
#pragma unroll
    for (int q = 0; q < 4; q++) {
        int dl = ty + q * 8;
        float v = W[(size_t)(d0 + dl) * FF + f0 + tx];
        tile[dl][tx] = v;
        ss += v * v;
    }
#pragma unroll
    for (int o = 32; o >= 1; o >>= 1) ss += __shfl_down(ss, o);
    if ((threadIdx.x & 63) == 0) {
        int slot = (blockIdx.x * 97 + blockIdx.y * 13 + (threadIdx.x >> 6)) & (NS2 - 1);
        atomicAdd(&s2part[slot], ss);
    }
    __syncthreads();
#pragma unroll
    for (int q = 0; q < 4; q++) {
        int fl = ty + q * 8;
        float v = tile[tx][fl];
        int f = f0 + fl, d = d0 + tx;
        Bp[pan_off8(f, d)] = f2e4m3(v * WSC);
        if (Wt32) Wt32[(size_t)f * DD + d] = v;
    }
}

// ---------------- prep: W_dec fp32 -> bf16 (halves decode gather traffic) ----------------
__global__ __launch_bounds__(256) void prep_wd_k(const float* __restrict__ Wd,
                                                 ushort* __restrict__ Wd16) {
    const int n4 = FF * DD / 4;
    for (int i = blockIdx.x * 256 + threadIdx.x; i < n4; i += gridDim.x * 256) {
        float4 v = ((const float4*)Wd)[i];
        ushort4 o;
        o.x = f2bf(v.x); o.y = f2bf(v.y); o.z = f2bf(v.z); o.w = f2bf(v.w);
        ((ushort4*)Wd16)[i] = o;
    }
}

// ---------------- per-row threshold: tau[b] = 2.75 * sqrt(mean(W^2)) * ||x_b - pb|| ----------------
__global__ __launch_bounds__(256) void rn_k(const float* __restrict__ x,
                                            const float* __restrict__ pb,
                                            const float* __restrict__ s2part,
                                            float* __restrict__ tau) {
    int t = threadIdx.x, l = t & 63, w = t >> 6;
    __shared__ float wsum[4];
    __shared__ float s2m;
    float p = s2part[t];  // NS2 == 256
#pragma unroll
    for (int o = 32; o >= 1; o >>= 1) p += __shfl_down(p, o);
    if (l == 0) wsum[w] = p;
    __syncthreads();
    if (t == 0) s2m = (wsum[0] + wsum[1] + wsum[2] + wsum[3]) / ((float)DD * (float)FF);
    __syncthreads();
    int row = blockIdx.x * 4 + w;
    float ss = 0.f;
#pragma unroll
    for (int q = 0; q < 12; q++) {
        int d = l + 64 * q;
        float v = x[(size_t)row * DD + d] - pb[d];
        ss += v * v;
    }
#pragma unroll
    for (int o = 32; o >= 1; o >>= 1) ss += __shfl_down(ss, o);
    if (l == 0) tau[row] = 2.75f * sqrtf(s2m * ss);
}

// ---- 128x128 fp8 MFMA GEMM, ring-3 BK=32, 1 barrier/kt, half-swap swizzled LDS, 3 blk/CU ----
// (r17-validated: MfmaUtil 63%, ~304 us). Epilogue writes per-(row,seg) count byte.
__global__ __launch_bounds__(256, 3) void gemm_k(const uchar* __restrict__ Ap,
                                                 const uchar* __restrict__ Bp,
                                                 const float* __restrict__ lbias,
                                                 const float* __restrict__ tau,
                                                 unsigned* __restrict__ cand,
                                                 uchar* __restrict__ ccnt8,
                                                 unsigned* __restrict__ rowbad) {
    __shared__ __align__(16) char smem[24576];   // 3 ring slots x (A 4K + B 4K)

    int bid = (int)blockIdx.x;                   // nwg = 16384, %8==0
    int wg = (bid & 7) * 2048 + (bid >> 3);      // bijective XCD swizzle
    int mt = wg >> 8, nt = wg & 255;             // per XCD: nt-major (A-tile L2 reuse)
    int m0 = mt << 7, n0 = nt << 7;

    int t = threadIdx.x, l = t & 63, w = t >> 6;
    int wm = w >> 1, wn = w & 1;                 // 2M x 2N

    // inverse-swizzled source offset (half-swap within 32-B row)
    int so = ((t >> 1) << 5) + (((t & 1) ^ ((t >> 3) & 1)) << 4);
    const uchar* sA = Ap + (size_t)mt * NKT * PQ8 + so;
    const uchar* sB = Bp + (size_t)nt * NKT * PQ8 + so;

    // swizzled frag read bases: r = wX*64 + i*16 + (l&15); g=(r>>2)&1 = (l>>2)&1
    int sw = ((l >> 2) & 1) << 1;
    int aro = ((wm << 6) + (l & 15)) * 32 + (((l >> 4) ^ sw) << 3);
    int bro = ((wn << 6) + (l & 15)) * 32 + (((l >> 4) ^ sw) << 3);

    f32x4 acc[4][4] = {};

#define STAGE(slot, kt)                                                       \
    {                                                                         \
        const size_t o = (size_t)(kt) * PQ8;                                  \
        char* base = smem + (slot) * 8192;                                    \
        gload_lds16(sA + o, base + t * 16);                                   \
        gload_lds16(sB + o, base + 4096 + t * 16);                            \
    }

    STAGE(0, 0)
    STAGE(1, 1)
    asm volatile("s_waitcnt vmcnt(2)" ::: "memory");
    __builtin_amdgcn_s_barrier();
    __builtin_amdgcn_sched_barrier(0);

    int cur = 0;
#pragma unroll 1
    for (int kt = 0; kt < NKT; kt++) {
        const char* As = smem + cur * 8192;
        const char* Bs = As + 4096;
        int nxt = cur + 2; if (nxt >= 3) nxt -= 3;
        if (kt < NKT - 2) STAGE(nxt, kt + 2)

        i64f af[4], bfr[4];
        af[0]  = *(const i64f*)(As + aro);
        af[1]  = *(const i64f*)(As + aro + 512);
        af[2]  = *(const i64f*)(As + aro + 1024);
        af[3]  = *(const i64f*)(As + aro + 1536);
        bfr[0] = *(const i64f*)(Bs + bro);
        bfr[1] = *(const i64f*)(Bs + bro + 512);
        bfr[2] = *(const i64f*)(Bs + bro + 1024);
        bfr[3] = *(const i64f*)(Bs + bro + 1536);
        asm volatile("s_waitcnt lgkmcnt(0)" ::: "memory");
        __builtin_amdgcn_sched_barrier(0);             // rule #18
        __builtin_amdgcn_s_setprio(1);
#pragma unroll
        for (int mi = 0; mi < 4; mi++)
#pragma unroll
            for (int ni = 0; ni < 4; ni++)
                acc[mi][ni] = __builtin_amdgcn_mfma_f32_16x16x32_fp8_fp8(
                    af[mi], bfr[ni], acc[mi][ni], 0, 0, 0);
        __builtin_amdgcn_s_setprio(0);
        __builtin_amdgcn_sched_barrier(0);
        if (kt < NKT - 2)
            asm volatile("s_waitcnt vmcnt(2)" ::: "memory");
        else
            asm volatile("s_waitcnt vmcnt(0)" ::: "memory");
        __builtin_amdgcn_s_barrier();
        __builtin_amdgcn_sched_barrier(0);
        cur = cur + 1; if (cur == 3) cur = 0;
    }
#undef STAGE

    // ---- epilogue: C/D map col=lane&15, row=(lane>>4)*4+j; de-scale; LDS-buffered append ----
    __syncthreads();
    int* lcnt = (int*)smem;                       // [128]
    unsigned* lbuf = (unsigned*)(smem + 512);     // [128][SLOT]
    if (t < 128) lcnt[t] = 0;
    __syncthreads();
    float lbv[4]; int fcol[4];
#pragma unroll
    for (int ni = 0; ni < 4; ni++) {
        fcol[ni] = n0 + wn * 64 + ni * 16 + (l & 15);
        lbv[ni] = lbias[fcol[ni]];
    }
#pragma unroll
    for (int mi = 0; mi < 4; mi++) {
        int rl = wm * 64 + mi * 16 + ((l >> 4) << 2);
        float4 tq = *(const float4*)(tau + m0 + rl);
        float tj[4] = {tq.x, tq.y, tq.z, tq.w};
#pragma unroll
        for (int ni = 0; ni < 4; ni++) {
            f32x4 v4 = acc[mi][ni];
#pragma unroll
            for (int j = 0; j < 4; j++) {
                float v = v4[j] * WSCI + lbv[ni];
                if (v >= tj[j]) {
                    int idx = rl + j;
                    int p = atomicAdd(&lcnt[idx], 1);
                    if (p < SLOT)
                        lbuf[idx * SLOT + p] =
                            ((unsigned)sortkey(f2bf(v)) << 16) | (unsigned)(32767 - fcol[ni]);
                }
            }
        }
    }
    __syncthreads();
    if (t < 128) {
        int c = lcnt[t];
        int gr = m0 + t;
        if (c > SLOT) { atomicOr(&rowbad[gr], 1u); c = SLOT; }
        unsigned* dstc = cand + (size_t)gr * (NSEG * SLOT) + nt * SLOT;
        for (int s2 = 0; s2 < c; s2++) dstc[s2] = lbuf[t * SLOT + s2];
        ccnt8[(size_t)gr * NSEG + nt] = (uchar)c;   // count protocol (no cand memset)
    }
}

// ------- per-row: gather counted entries, sort, keep top-RUNC; flag pathological rows -------
__global__ __launch_bounds__(256) void select2_k(const unsigned* __restrict__ cand,
                                                 const uchar* __restrict__ ccnt8,
                                                 const unsigned* __restrict__ rowbad,
                                                 unsigned* __restrict__ flagv,
                                                 int* __restrict__ ridx,
                                                 int* __restrict__ runcnt) {
    int b = blockIdx.x, t = threadIdx.x;
    __shared__ unsigned srt[SORTN];
    __shared__ int s_cnt;
    for (int i = t; i < SORTN; i += 256) srt[i] = 0;
    if (t == 0) s_cnt = 0;
    __syncthreads();
    const uchar* cc = ccnt8 + (size_t)b * NSEG;
    const unsigned* base = cand + (size_t)b * (NSEG * SLOT);
    for (int seg = t; seg < NSEG; seg += 256) {
        int c = cc[seg];
        const unsigned* e = base + seg * SLOT;
        for (int q = 0; q < c; q++) {
            int p = atomicAdd(&s_cnt, 1);
            if (p < SORTN) srt[p] = e[q];
        }
    }
    __syncthreads();
    int cnt = s_cnt;
    int bad = (rowbad[b] != 0u) || cnt < 48 || cnt > SORTN;
    if (t == 0) { flagv[b] = bad; if (bad) runcnt[b] = 0; }
    if (bad) return;
    for (int k = 2; k <= SORTN; k <<= 1) {
        for (int j = k >> 1; j > 0; j >>= 1) {
#pragma unroll
            for (int q = 0; q < SORTN / 256; q++) {
                int i = t + q * 256;
                int ixj = i ^ j;
                if (ixj > i) {
                    unsigned a = srt[i], c2 = srt[ixj];
                    bool sw = ((i & k) == 0) ? (a < c2) : (a > c2);
                    if (sw) { srt[i] = c2; srt[ixj] = a; }
                }
            }
            __syncthreads();
        }
    }
    int nc = cnt < RUNC ? cnt : RUNC;
    if (t < nc) ridx[(size_t)b * RUNC + t] = 32767 - (int)(srt[t] & 0xFFFFu);
    if (t == 0) runcnt[b] = nc;
}

// ---------------- exact fallback for flagged rows (expected ~0 rows; LUT-fast) ----------------
__global__ __launch_bounds__(256) void fb_k(const unsigned* __restrict__ flagv,
                                            const float* __restrict__ x,
                                            const float* __restrict__ pb,
                                            const uchar* __restrict__ Bp,
                                            const float* __restrict__ lb,
                                            int* __restrict__ ridx,
                                            int* __restrict__ runcnt) {
    int b = blockIdx.x;
    if (!flagv[b]) return;
    int t = threadIdx.x;
    __shared__ float xs[DD];
    __shared__ float lut[256];
    __shared__ unsigned hist[256];
    __shared__ int s_cb, s_cum, s_T, s_pos;
    for (int i = t; i < DD; i += 256) xs[i] = x[(size_t)b * DD + i] - pb[i];
    lut[t] = e4m3f((uchar)t) * WSCI;
    hist[t] = 0;
    if (t == 0) s_pos = 0;
    __syncthreads();

#define FBDOT(f, sdst)                                                        \
    {                                                                         \
        const uchar* fr = Bp + ((size_t)((f) >> 7) * NKT) * PQ8 + (((f) & 127) << 5); \
        float s_ = 0.f;                                                       \
        for (int kt = 0; kt < NKT; kt++) {                                    \
            const unsigned* pw = (const unsigned*)(fr + (size_t)kt * PQ8);    \
            _Pragma("unroll")                                                 \
            for (int q = 0; q < 8; q++) {                                     \
                unsigned wv = pw[q];                                          \
                s_ += xs[kt * 32 + q * 4 + 0] * lut[wv & 255];                \
                s_ += xs[kt * 32 + q * 4 + 1] * lut[(wv >> 8) & 255];         \
                s_ += xs[kt * 32 + q * 4 + 2] * lut[(wv >> 16) & 255];        \
                s_ += xs[kt * 32 + q * 4 + 3] * lut[wv >> 24];                \
            }                                                                 \
        }                                                                     \
        sdst = s_;                                                            \
    }

    for (int f = t; f < FF; f += 256) {
        float s; FBDOT(f, s)
        ushort k = sortkey(f2bf(s + lb[f]));
        atomicAdd(&hist[k >> 8], 1u);
    }
    __syncthreads();
    if (t == 0) {
        int cum = 0, cb2 = 0;
        for (int i = 255; i >= 0; i--) {
            if (cum + (int)hist[i] >= 48) { cb2 = i; break; }
            cum += (int)hist[i];
        }
        s_cb = cb2; s_cum = cum;
    }
    __syncthreads();
    int cb2 = s_cb;
    hist[t] = 0;
    __syncthreads();
    for (int f = t; f < FF; f += 256) {
        float s; FBDOT(f, s)
        ushort k = sortkey(f2bf(s + lb[f]));
        if ((int)(k >> 8) == cb2) atomicAdd(&hist[k & 0xFF], 1u);
    }
    __syncthreads();
    if (t == 0) {
        int cum = s_cum, T = cb2 << 8;
        for (int fb2 = 255; fb2 >= 0; fb2--) {
            if (cum + (int)hist[fb2] >= 48) { T = (cb2 << 8) | fb2; break; }
            cum += (int)hist[fb2];
        }
        s_T = T;
    }
    __syncthreads();
    unsigned T = (unsigned)s_T;
    for (int f = t; f < FF; f += 256) {
        float s; FBDOT(f, s)
        ushort k = sortkey(f2bf(s + lb[f]));
        if (k >= T) {
            int p = atomicAdd(&s_pos, 1);
            if (p < RUNC) ridx[(size_t)b * RUNC + p] = f;
        }
    }
#undef FBDOT
    __syncthreads();
    if (t == 0) runcnt[b] = s_pos < RUNC ? s_pos : RUNC;
}

// ---- refine + decode fused: fp64 re-dot (8 waves deep), exact top-32, bf16 decode ----
__global__ __launch_bounds__(512) void refdec_k(const float* __restrict__ x,
                                                const float* __restrict__ pb,
                                                const float* __restrict__ We,
                                                const float* __restrict__ Wt32,
                                                const float* __restrict__ lb,
                                                const int* __restrict__ runidx,
                                                const int* __restrict__ runcnt,
                                                int use_t,
                                                const ushort* __restrict__ Wd16,
                                                const float* __restrict__ Wd,
                                                float* __restrict__ out) {
    int b = blockIdx.x, t = threadIdx.x, l = t & 63, w = t >> 6;  // 8 waves
    __shared__ float xs[DD];
    __shared__ int ci[RUNC];
    __shared__ float cv[RUNC];
    __shared__ int si[TK];
    __shared__ float sv[TK];
    for (int i = t; i < DD; i += 512) xs[i] = x[(size_t)b * DD + i] - pb[i];
    int c = runcnt[b]; if (c > RUNC) c = RUNC;
    if (t < RUNC) cv[t] = -1e30f;
    if (t < c) ci[t] = runidx[(size_t)b * RUNC + t];
    __syncthreads();
    // 8 waves x 8 candidate rounds (halved gather-latency chain vs 4x16)
    for (int j = w; j < c; j += 8) {
        int f = ci[j];
        double s = 0.0;
        if (use_t) {
            const float* wr = Wt32 + (size_t)f * DD;
#pragma unroll
            for (int q = 0; q < 12; q++)
                s = fma((double)wr[l + 64 * q], (double)xs[l + 64 * q], s);
        } else {
#pragma unroll
            for (int q = 0; q < 12; q++)
                s = fma((double)We[(size_t)(l + 64 * q) * FF + f], (double)xs[l + 64 * q], s);
        }
#pragma unroll
        for (int o = 32; o >= 1; o >>= 1) s += __shfl_down(s, o);
        if (l == 0) cv[j] = (float)(s + (double)lb[f]);
    }
    __syncthreads();
    if (w == 0) {
        float v0 = (l < RUNC) ? cv[l] : -1e30f;
        int i0 = (l < c) ? ci[l] : 0x7FFFFFFF;
        for (int sel = 0; sel < TK; sel++) {
            float bv = v0; int bi = i0;
#pragma unroll
            for (int o = 32; o >= 1; o >>= 1) {
                float ov = __shfl_xor(bv, o);
                int oi = __shfl_xor(bi, o);
                if (ov > bv || (ov == bv && oi < bi)) { bv = ov; bi = oi; }
            }
            if (i0 == bi) v0 = -1e30f;
            if (l == 0) {
                if (bi == 0x7FFFFFFF) { bi = 0; bv = -1e30f; }
                si[sel] = bi;
                sv[sel] = bv > 0.f ? bv : 0.f;
            }
        }
    }
    __syncthreads();
    // decode phase: threads 0..191, one float4 of the 768-dim output each
    if (t < DD / 4) {
        float4 acc = ((const float4*)pb)[t];
        if (Wd16) {
#pragma unroll 4
            for (int j = 0; j < TK; j++) {
                float v = sv[j];
                ushort4 wv = ((const ushort4*)(Wd16 + (size_t)si[j] * DD))[t];
                acc.x += v * bf2f(wv.x); acc.y += v * bf2f(wv.y);
                acc.z += v * bf2f(wv.z); acc.w += v * bf2f(wv.w);
            }
        } else {
#pragma unroll 4
            for (int j = 0; j < TK; j++) {
                float v = sv[j];
                float4 wv = ((const float4*)(Wd + (size_t)si[j] * DD))[t];
                acc.x += v * wv.x; acc.y += v * wv.y;
                acc.z += v * wv.z; acc.w += v * wv.w;
            }
        }
        ((float4*)out)[(size_t)b * (DD / 4) + t] = acc;
    }
}

extern "C" void kernel_launch(void* const* d_in, const int* in_sizes, int n_in,
                              void* d_out, int out_size, void* d_ws, size_t ws_size,
                              hipStream_t stream) {
    const float* x  = (const float*)d_in[0];
    const float* pb = (const float*)d_in[1];
    const float* We = (const float*)d_in[2];
    const float* lb = (const float*)d_in[3];
    const float* Wd = (const float*)d_in[4];
    float* out = (float*)d_out;
    char* ws = (char*)d_ws;
    (void)in_sizes; (void)n_in; (void)out_size;

    const size_t SZ_AP   = (size_t)NB * DD;                  // 6.3 MB (fp8)
    const size_t SZ_BP   = (size_t)FF * DD;                  // 25.2 MB (fp8)
    const size_t SZ_WT32 = (size_t)FF * DD * 4;              // 100.7 MB
    const size_t SZ_WD16 = (size_t)FF * DD * 2;              // 50.3 MB
    const size_t SZ_CAND = (size_t)NB * NSEG * SLOT * 4;     // 67.1 MB (NOT memset)
    const size_t SZ_CC8  = (size_t)NB * NSEG;                // 2.1 MB (fully written by gemm)
    const size_t SZ_TAU  = (size_t)NB * 4;
    const size_t SZ_RIDX = (size_t)NB * RUNC * 4;
    const size_t SZ_RCNT = (size_t)NB * 4;

    size_t need_base = SZ_AP + SZ_BP + SZ_CAND + SZ_CC8 + (size_t)NB * 8 + NS2 * 4 +
                       SZ_TAU + SZ_RIDX + SZ_RCNT;
    int use_t = (ws_size >= need_base + SZ_WT32 + SZ_WD16) ? 1 : 0;

    size_t off = 0;
    uchar* Ap     = (uchar*)(ws + off); off += SZ_AP;
    uchar* Bp     = (uchar*)(ws + off); off += SZ_BP;
    float* Wt32   = nullptr;
    ushort* Wd16  = nullptr;
    if (use_t) {
        Wt32 = (float*)(ws + off); off += SZ_WT32;
        Wd16 = (ushort*)(ws + off); off += SZ_WD16;
    }
    char* ctrl0   = (char*)(ws + off);                       // memset region: rowbad + s2part
    unsigned* rowbad = (unsigned*)(ws + off); off += (size_t)NB * 4;
    float* s2part = (float*)(ws + off); off += NS2 * 4;
    size_t ctrl_bytes = (size_t)((ws + off) - ctrl0);
    unsigned* cand = (unsigned*)(ws + off); off += SZ_CAND;
    uchar* ccnt8  = (uchar*)(ws + off); off += SZ_CC8;
    unsigned* flagv = (unsigned*)(ws + off); off += (size_t)NB * 4;
    float* tau    = (float*)(ws + off); off += SZ_TAU;
    int* ridx     = (int*)(ws + off); off += SZ_RIDX;
    int* rcnt     = (int*)(ws + off); off += SZ_RCNT;

    hipMemsetAsync(ctrl0, 0, ctrl_bytes, stream);
    prep_x_k<<<2048, 256, 0, stream>>>(x, pb, Ap);
    prep_w_k<<<dim3(FF / 32, DD / 32), 256, 0, stream>>>(We, Bp, Wt32, s2part);
    if (use_t) prep_wd_k<<<2048, 256, 0, stream>>>(Wd, Wd16);
    rn_k<<<NB / 4, 256, 0, stream>>>(x, pb, s2part, tau);
    gemm_k<<<(NB / 128) * (FF / 128), 256, 0, stream>>>(Ap, Bp, lb, tau, cand, ccnt8, rowbad);
    select2_k<<<NB, 256, 0, stream>>>(cand, ccnt8, rowbad, flagv, ridx, rcnt);
    fb_k<<<NB, 256, 0, stream>>>(flagv, x, pb, Bp, lb, ridx, rcnt);
    refdec_k<<<NB, 512, 0, stream>>>(x, pb, We, Wt32, lb, ridx, rcnt, use_t,
                                     Wd16, Wd, out);
}

// Round 20
// 890.781 us; speedup vs baseline: 1.2682x; 1.2682x over previous
//
#include <hip/hip_runtime.h>
#include <stdint.h>

#define GAS __attribute__((address_space(1)))
#define LAS __attribute__((address_space(3)))

typedef __attribute__((ext_vector_type(4))) float f32x4;
typedef unsigned char uchar;
typedef long long i64f;

static constexpr int NB = 8192;    // batch
static constexpr int DD = 768;     // model dim (K)
static constexpr int FF = 32768;   // latent dim (N)
static constexpr int TK = 32;      // top-k
static constexpr int RUNC = 64;    // refined candidate cap
static constexpr int SLOT = 8;     // survivor slots per (row, 128-col segment)
static constexpr int NSEG = FF / 128;  // 256 segments per row
static constexpr int SORTN = 1024; // select2 sort size
static constexpr int NS2 = 256;    // partial-sum slots for mean(W^2)
static constexpr int NKT = DD / 32;    // 24 K-tiles of 32
static constexpr int PQ8 = 128 * 32;   // panel BYTES per K-tile (4 KB, 128-row tiles)
// W scaled by 64 before e4m3: w*64 ~ N(0,0.49) in e4m3 NORMAL range (r13/r14 lesson)
static constexpr float WSC = 64.0f;
static constexpr float WSCI = 1.0f / 64.0f;

__device__ __forceinline__ ushort f2bf(float f) {
    unsigned x = __float_as_uint(f);
    unsigned r = (x + 0x7FFFu + ((x >> 16) & 1u)) >> 16;
    return (ushort)r;
}
__device__ __forceinline__ ushort sortkey(ushort u) {
    return (u & 0x8000u) ? (ushort)(u ^ 0xFFFFu) : (ushort)(u | 0x8000u);
}
__device__ __forceinline__ float bf2f(ushort u) {
    return __uint_as_float(((unsigned)u) << 16);
}
__device__ __forceinline__ float e4m3f(uchar b) {
    int e = (b >> 3) & 0xF, m = b & 7;
    float v = (e == 0) ? ldexpf((float)m, -9) : ldexpf((float)(8 + m), e - 10);
    return (b & 0x80) ? -v : v;
}
__device__ __forceinline__ uchar f2e4m3(float v) {
    return (uchar)(__builtin_amdgcn_cvt_pk_fp8_f32(v, v, 0, false) & 0xFF);
}
__device__ __forceinline__ void gload_lds16(const void* g, void* l) {
    __builtin_amdgcn_global_load_lds((const GAS unsigned int*)g,
                                     (LAS unsigned int*)l, 16, 0, 0);
}
// panel BYTE offset: [vtile=v>>7][kt=d>>5][v&127][d&31]  (row-major 32-B rows)
__device__ __forceinline__ size_t pan_off8(int v, int d) {
    return ((size_t)(v >> 7) * NKT + (d >> 5)) * PQ8 + ((v & 127) << 5) + (d & 31);
}

// ---------------- prep: A panels = e4m3(x - pre_bias), packed ----------------
__global__ __launch_bounds__(256) void prep_x_k(const float* __restrict__ x,
                                                const float* __restrict__ pb,
                                                uchar* __restrict__ Ap) {
    const int n4 = NB * DD / 4;
    for (int i = blockIdx.x * 256 + threadIdx.x; i < n4; i += gridDim.x * 256) {
        int b = i / (DD / 4), dq = (i % (DD / 4)) * 4;
        float4 v = ((const float4*)x)[i];
        float4 p = ((const float4*)pb)[i % (DD / 4)];
        int w = __builtin_amdgcn_cvt_pk_fp8_f32(v.x - p.x, v.y - p.y, 0, false);
        w = __builtin_amdgcn_cvt_pk_fp8_f32(v.z - p.z, v.w - p.w, w, true);
        *(unsigned*)(Ap + pan_off8(b, dq)) = (unsigned)w;
    }
}

// ------------- prep: W_enc [D,F] -> B panels (e4m3, x64 scaled) + Wt32 [F,D] + sum(W^2) -------------
__global__ __launch_bounds__(256) void prep_w_k(const float* __restrict__ W,
                                                uchar* __restrict__ Bp,
                                                float* __restrict__ Wt32,
                                                float* __restrict__ s2part) {
    __shared__ float tile[32][33];
    int f0 = blockIdx.x * 32, d0 = blockIdx.y * 32;
    int tx = threadIdx.x & 31, ty = threadIdx.x >> 5;  // ty 0..7
    float ss = 0.f;
#pragma unroll
    for (int q = 0; q < 4; q++) {
        int dl = ty + q * 8;
        float v = W[(size_t)(d0 + dl) * FF + f0 + tx];
        tile[dl][tx] = v;
        ss += v * v;
    }
#pragma unroll
    for (int o = 32; o >= 1; o >>= 1) ss += __shfl_down(ss, o);
    if ((threadIdx.x & 63) == 0) {
        int slot = (blockIdx.x * 97 + blockIdx.y * 13 + (threadIdx.x >> 6)) & (NS2 - 1);
        atomicAdd(&s2part[slot], ss);
    }
    __syncthreads();
#pragma unroll
    for (int q = 0; q < 4; q++) {
        int fl = ty + q * 8;
        float v = tile[tx][fl];
        int f = f0 + fl, d = d0 + tx;
        Bp[pan_off8(f, d)] = f2e4m3(v * WSC);
        if (Wt32) Wt32[(size_t)f * DD + d] = v;
    }
}

// ---------------- prep: W_dec fp32 -> bf16 (halves decode gather traffic) ----------------
__global__ __launch_bounds__(256) void prep_wd_k(const float* __restrict__ Wd,
                                                 ushort* __restrict__ Wd16) {
    const int n4 = FF * DD / 4;
    for (int i = blockIdx.x * 256 + threadIdx.x; i < n4; i += gridDim.x * 256) {
        float4 v = ((const float4*)Wd)[i];
        ushort4 o;
        o.x = f2bf(v.x); o.y = f2bf(v.y); o.z = f2bf(v.z); o.w = f2bf(v.w);
        ((ushort4*)Wd16)[i] = o;
    }
}

// ---------------- per-row threshold: tau[b] = 2.75 * sqrt(mean(W^2)) * ||x_b - pb|| ----------------
__global__ __launch_bounds__(256) void rn_k(const float* __restrict__ x,
                                            const float* __restrict__ pb,
                                            const float* __restrict__ s2part,
                                            float* __restrict__ tau) {
    int t = threadIdx.x, l = t & 63, w = t >> 6;
    __shared__ float wsum[4];
    __shared__ float s2m;
    float p = s2part[t];  // NS2 == 256
#pragma unroll
    for (int o = 32; o >= 1; o >>= 1) p += __shfl_down(p, o);
    if (l == 0) wsum[w] = p;
    __syncthreads();
    if (t == 0) s2m = (wsum[0] + wsum[1] + wsum[2] + wsum[3]) / ((float)DD * (float)FF);
    __syncthreads();
    int row = blockIdx.x * 4 + w;
    float ss = 0.f;
#pragma unroll
    for (int q = 0; q < 12; q++) {
        int d = l + 64 * q;
        float v = x[(size_t)row * DD + d] - pb[d];
        ss += v * v;
    }
#pragma unroll
    for (int o = 32; o >= 1; o >>= 1) ss += __shfl_down(ss, o);
    if (l == 0) tau[row] = 2.75f * sqrtf(s2m * ss);
}

// ---- 128x128 fp8 MFMA GEMM, ring-3 BK=32, 1 barrier/kt, half-swap swizzled LDS, 3 blk/CU ----
// (r17-validated: MfmaUtil 63%, ~304 us). Epilogue writes per-(row,seg) count byte.
__global__ __launch_bounds__(256, 3) void gemm_k(const uchar* __restrict__ Ap,
                                                 const uchar* __restrict__ Bp,
                                                 const float* __restrict__ lbias,
                                                 const float* __restrict__ tau,
                                                 unsigned* __restrict__ cand,
                                                 uchar* __restrict__ ccnt8,
                                                 unsigned* __restrict__ rowbad) {
    __shared__ __align__(16) char smem[24576];   // 3 ring slots x (A 4K + B 4K)

    int bid = (int)blockIdx.x;                   // nwg = 16384, %8==0
    int wg = (bid & 7) * 2048 + (bid >> 3);      // bijective XCD swizzle
    int mt = wg >> 8, nt = wg & 255;             // per XCD: nt-major (A-tile L2 reuse)
    int m0 = mt << 7, n0 = nt << 7;

    int t = threadIdx.x, l = t & 63, w = t >> 6;
    int wm = w >> 1, wn = w & 1;                 // 2M x 2N

    // inverse-swizzled source offset (half-swap within 32-B row)
    int so = ((t >> 1) << 5) + (((t & 1) ^ ((t >> 3) & 1)) << 4);
    const uchar* sA = Ap + (size_t)mt * NKT * PQ8 + so;
    const uchar* sB = Bp + (size_t)nt * NKT * PQ8 + so;

    // swizzled frag read bases: r = wX*64 + i*16 + (l&15); g=(r>>2)&1 = (l>>2)&1
    int sw = ((l >> 2) & 1) << 1;
    int aro = ((wm << 6) + (l & 15)) * 32 + (((l >> 4) ^ sw) << 3);
    int bro = ((wn << 6) + (l & 15)) * 32 + (((l >> 4) ^ sw) << 3);

    f32x4 acc[4][4] = {};

#define STAGE(slot, kt)                                                       \
    {                                                                         \
        const size_t o = (size_t)(kt) * PQ8;                                  \
        char* base = smem + (slot) * 8192;                                    \
        gload_lds16(sA + o, base + t * 16);                                   \
        gload_lds16(sB + o, base + 4096 + t * 16);                            \
    }

    STAGE(0, 0)
    STAGE(1, 1)
    asm volatile("s_waitcnt vmcnt(2)" ::: "memory");
    __builtin_amdgcn_s_barrier();
    __builtin_amdgcn_sched_barrier(0);

    int cur = 0;
#pragma unroll 1
    for (int kt = 0; kt < NKT; kt++) {
        const char* As = smem + cur * 8192;
        const char* Bs = As + 4096;
        int nxt = cur + 2; if (nxt >= 3) nxt -= 3;
        if (kt < NKT - 2) STAGE(nxt, kt + 2)

        i64f af[4], bfr[4];
        af[0]  = *(const i64f*)(As + aro);
        af[1]  = *(const i64f*)(As + aro + 512);
        af[2]  = *(const i64f*)(As + aro + 1024);
        af[3]  = *(const i64f*)(As + aro + 1536);
        bfr[0] = *(const i64f*)(Bs + bro);
        bfr[1] = *(const i64f*)(Bs + bro + 512);
        bfr[2] = *(const i64f*)(Bs + bro + 1024);
        bfr[3] = *(const i64f*)(Bs + bro + 1536);
        asm volatile("s_waitcnt lgkmcnt(0)" ::: "memory");
        __builtin_amdgcn_sched_barrier(0);             // rule #18
        __builtin_amdgcn_s_setprio(1);
#pragma unroll
        for (int mi = 0; mi < 4; mi++)
#pragma unroll
            for (int ni = 0; ni < 4; ni++)
                acc[mi][ni] = __builtin_amdgcn_mfma_f32_16x16x32_fp8_fp8(
                    af[mi], bfr[ni], acc[mi][ni], 0, 0, 0);
        __builtin_amdgcn_s_setprio(0);
        __builtin_amdgcn_sched_barrier(0);
        if (kt < NKT - 2)
            asm volatile("s_waitcnt vmcnt(2)" ::: "memory");
        else
            asm volatile("s_waitcnt vmcnt(0)" ::: "memory");
        __builtin_amdgcn_s_barrier();
        __builtin_amdgcn_sched_barrier(0);
        cur = cur + 1; if (cur == 3) cur = 0;
    }
#undef STAGE

    // ---- epilogue: C/D map col=lane&15, row=(lane>>4)*4+j; de-scale; LDS-buffered append ----
    __syncthreads();
    int* lcnt = (int*)smem;                       // [128]
    unsigned* lbuf = (unsigned*)(smem + 512);     // [128][SLOT]
    if (t < 128) lcnt[t] = 0;
    __syncthreads();
    float lbv[4]; int fcol[4];
#pragma unroll
    for (int ni = 0; ni < 4; ni++) {
        fcol[ni] = n0 + wn * 64 + ni * 16 + (l & 15);
        lbv[ni] = lbias[fcol[ni]];
    }
#pragma unroll
    for (int mi = 0; mi < 4; mi++) {
        int rl = wm * 64 + mi * 16 + ((l >> 4) << 2);
        float4 tq = *(const float4*)(tau + m0 + rl);
        float tj[4] = {tq.x, tq.y, tq.z, tq.w};
#pragma unroll
        for (int ni = 0; ni < 4; ni++) {
            f32x4 v4 = acc[mi][ni];
#pragma unroll
            for (int j = 0; j < 4; j++) {
                float v = v4[j] * WSCI + lbv[ni];
                if (v >= tj[j]) {
                    int idx = rl + j;
                    int p = atomicAdd(&lcnt[idx], 1);
                    if (p < SLOT)
                        lbuf[idx * SLOT + p] =
                            ((unsigned)sortkey(f2bf(v)) << 16) | (unsigned)(32767 - fcol[ni]);
                }
            }
        }
    }
    __syncthreads();
    if (t < 128) {
        int c = lcnt[t];
        int gr = m0 + t;
        if (c > SLOT) { atomicOr(&rowbad[gr], 1u); c = SLOT; }
        unsigned* dstc = cand + (size_t)gr * (NSEG * SLOT) + nt * SLOT;
        for (int s2 = 0; s2 < c; s2++) dstc[s2] = lbuf[t * SLOT + s2];
        ccnt8[(size_t)gr * NSEG + nt] = (uchar)c;   // count protocol (no cand memset)
    }
}

// ------- per-row: gather counted entries, sort, keep top-RUNC; flag pathological rows -------
__global__ __launch_bounds__(256) void select2_k(const unsigned* __restrict__ cand,
                                                 const uchar* __restrict__ ccnt8,
                                                 const unsigned* __restrict__ rowbad,
                                                 unsigned* __restrict__ flagv,
                                                 int* __restrict__ ridx,
                                                 int* __restrict__ runcnt) {
    int b = blockIdx.x, t = threadIdx.x;
    __shared__ unsigned srt[SORTN];
    __shared__ int s_cnt;
    for (int i = t; i < SORTN; i += 256) srt[i] = 0;
    if (t == 0) s_cnt = 0;
    __syncthreads();
    const uchar* cc = ccnt8 + (size_t)b * NSEG;
    const unsigned* base = cand + (size_t)b * (NSEG * SLOT);
    for (int seg = t; seg < NSEG; seg += 256) {
        int c = cc[seg];
        const unsigned* e = base + seg * SLOT;
        for (int q = 0; q < c; q++) {
            int p = atomicAdd(&s_cnt, 1);
            if (p < SORTN) srt[p] = e[q];
        }
    }
    __syncthreads();
    int cnt = s_cnt;
    int bad = (rowbad[b] != 0u) || cnt < 48 || cnt > SORTN;
    if (t == 0) { flagv[b] = bad; if (bad) runcnt[b] = 0; }
    if (bad) return;
    for (int k = 2; k <= SORTN; k <<= 1) {
        for (int j = k >> 1; j > 0; j >>= 1) {
#pragma unroll
            for (int q = 0; q < SORTN / 256; q++) {
                int i = t + q * 256;
                int ixj = i ^ j;
                if (ixj > i) {
                    unsigned a = srt[i], c2 = srt[ixj];
                    bool sw = ((i & k) == 0) ? (a < c2) : (a > c2);
                    if (sw) { srt[i] = c2; srt[ixj] = a; }
                }
            }
            __syncthreads();
        }
    }
    int nc = cnt < RUNC ? cnt : RUNC;
    if (t < nc) ridx[(size_t)b * RUNC + t] = 32767 - (int)(srt[t] & 0xFFFFu);
    if (t == 0) runcnt[b] = nc;
}

// ---------------- exact fallback for flagged rows (expected ~0 rows; LUT-fast) ----------------
__global__ __launch_bounds__(256) void fb_k(const unsigned* __restrict__ flagv,
                                            const float* __restrict__ x,
                                            const float* __restrict__ pb,
                                            const uchar* __restrict__ Bp,
                                            const float* __restrict__ lb,
                                            int* __restrict__ ridx,
                                            int* __restrict__ runcnt) {
    int b = blockIdx.x;
    if (!flagv[b]) return;
    int t = threadIdx.x;
    __shared__ float xs[DD];
    __shared__ float lut[256];
    __shared__ unsigned hist[256];
    __shared__ int s_cb, s_cum, s_T, s_pos;
    for (int i = t; i < DD; i += 256) xs[i] = x[(size_t)b * DD + i] - pb[i];
    lut[t] = e4m3f((uchar)t) * WSCI;
    hist[t] = 0;
    if (t == 0) s_pos = 0;
    __syncthreads();

#define FBDOT(f, sdst)                                                        \
    {                                                                         \
        const uchar* fr = Bp + ((size_t)((f) >> 7) * NKT) * PQ8 + (((f) & 127) << 5); \
        float s_ = 0.f;                                                       \
        for (int kt = 0; kt < NKT; kt++) {                                    \
            const unsigned* pw = (const unsigned*)(fr + (size_t)kt * PQ8);    \
            _Pragma("unroll")                                                 \
            for (int q = 0; q < 8; q++) {                                     \
                unsigned wv = pw[q];                                          \
                s_ += xs[kt * 32 + q * 4 + 0] * lut[wv & 255];                \
                s_ += xs[kt * 32 + q * 4 + 1] * lut[(wv >> 8) & 255];         \
                s_ += xs[kt * 32 + q * 4 + 2] * lut[(wv >> 16) & 255];        \
                s_ += xs[kt * 32 + q * 4 + 3] * lut[wv >> 24];                \
            }                                                                 \
        }                                                                     \
        sdst = s_;                                                            \
    }

    for (int f = t; f < FF; f += 256) {
        float s; FBDOT(f, s)
        ushort k = sortkey(f2bf(s + lb[f]));
        atomicAdd(&hist[k >> 8], 1u);
    }
    __syncthreads();
    if (t == 0) {
        int cum = 0, cb2 = 0;
        for (int i = 255; i >= 0; i--) {
            if (cum + (int)hist[i] >= 48) { cb2 = i; break; }
            cum += (int)hist[i];
        }
        s_cb = cb2; s_cum = cum;
    }
    __syncthreads();
    int cb2 = s_cb;
    hist[t] = 0;
    __syncthreads();
    for (int f = t; f < FF; f += 256) {
        float s; FBDOT(f, s)
        ushort k = sortkey(f2bf(s + lb[f]));
        if ((int)(k >> 8) == cb2) atomicAdd(&hist[k & 0xFF], 1u);
    }
    __syncthreads();
    if (t == 0) {
        int cum = s_cum, T = cb2 << 8;
        for (int fb2 = 255; fb2 >= 0; fb2--) {
            if (cum + (int)hist[fb2] >= 48) { T = (cb2 << 8) | fb2; break; }
            cum += (int)hist[fb2];
        }
        s_T = T;
    }
    __syncthreads();
    unsigned T = (unsigned)s_T;
    for (int f = t; f < FF; f += 256) {
        float s; FBDOT(f, s)
        ushort k = sortkey(f2bf(s + lb[f]));
        if (k >= T) {
            int p = atomicAdd(&s_pos, 1);
            if (p < RUNC) ridx[(size_t)b * RUNC + p] = f;
        }
    }
#undef FBDOT
    __syncthreads();
    if (t == 0) runcnt[b] = s_pos < RUNC ? s_pos : RUNC;
}

// ---------------- refine: fp64 re-dot (2-way ILP split), exact top-32 ----------------
__global__ __launch_bounds__(256) void refine_k(const float* __restrict__ x,
                                                const float* __restrict__ pb,
                                                const float* __restrict__ We,
                                                const float* __restrict__ Wt32,
                                                const float* __restrict__ lb,
                                                const int* __restrict__ runidx,
                                                const int* __restrict__ runcnt,
                                                int use_t,
                                                int* __restrict__ sidx,
                                                float* __restrict__ sval) {
    int b = blockIdx.x, t = threadIdx.x, l = t & 63, w = t >> 6;
    __shared__ float xs[DD];
    __shared__ int ci[RUNC];
    __shared__ float cv[RUNC];
    for (int i = t; i < DD; i += 256) xs[i] = x[(size_t)b * DD + i] - pb[i];
    int c = runcnt[b]; if (c > RUNC) c = RUNC;
    if (t < RUNC) cv[t] = -1e30f;
    if (t < c) ci[t] = runidx[(size_t)b * RUNC + t];
    __syncthreads();
    for (int j = w; j < c; j += 4) {
        int f = ci[j];
        double s0 = 0.0, s1 = 0.0;   // 2-accumulator ILP (fp64 fma chain split)
        if (use_t) {
            const float* wr = Wt32 + (size_t)f * DD;
#pragma unroll
            for (int q = 0; q < 6; q++) {
                s0 = fma((double)wr[l + 128 * q], (double)xs[l + 128 * q], s0);
                s1 = fma((double)wr[l + 64 + 128 * q], (double)xs[l + 64 + 128 * q], s1);
            }
        } else {
#pragma unroll
            for (int q = 0; q < 6; q++) {
                s0 = fma((double)We[(size_t)(l + 128 * q) * FF + f], (double)xs[l + 128 * q], s0);
                s1 = fma((double)We[(size_t)(l + 64 + 128 * q) * FF + f], (double)xs[l + 64 + 128 * q], s1);
            }
        }
        double s = s0 + s1;
#pragma unroll
        for (int o = 32; o >= 1; o >>= 1) s += __shfl_down(s, o);
        if (l == 0) cv[j] = (float)(s + (double)lb[f]);
    }
    __syncthreads();
    if (w == 0) {
        float v0 = (l < RUNC) ? cv[l] : -1e30f;
        int i0 = (l < c) ? ci[l] : 0x7FFFFFFF;
        for (int sel = 0; sel < TK; sel++) {
            float bv = v0; int bi = i0;
#pragma unroll
            for (int o = 32; o >= 1; o >>= 1) {
                float ov = __shfl_xor(bv, o);
                int oi = __shfl_xor(bi, o);
                if (ov > bv || (ov == bv && oi < bi)) { bv = ov; bi = oi; }
            }
            if (i0 == bi) v0 = -1e30f;
            if (l == 0) {
                if (bi == 0x7FFFFFFF) { bi = 0; bv = -1e30f; }
                sidx[(size_t)b * TK + sel] = bi;
                sval[(size_t)b * TK + sel] = bv > 0.f ? bv : 0.f;
            }
        }
    }
}

// ---------------- decode: bf16 W_dec gathers (half traffic), fp32 accumulate ----------------
__global__ __launch_bounds__(192) void decode_k(const float* __restrict__ sval,
                                                const int* __restrict__ sidx,
                                                const ushort* __restrict__ Wd16,
                                                const float* __restrict__ Wd,
                                                const float* __restrict__ pb,
                                                float* __restrict__ out) {
    int b = blockIdx.x, t = threadIdx.x;
    __shared__ float sv[TK];
    __shared__ int si[TK];
    if (t < TK) { sv[t] = sval[(size_t)b * TK + t]; si[t] = sidx[(size_t)b * TK + t]; }
    __syncthreads();
    float4 acc = ((const float4*)pb)[t];
    if (Wd16) {
#pragma unroll 4
        for (int j = 0; j < TK; j++) {
            float v = sv[j];
            ushort4 wv = ((const ushort4*)(Wd16 + (size_t)si[j] * DD))[t];
            acc.x += v * bf2f(wv.x); acc.y += v * bf2f(wv.y);
            acc.z += v * bf2f(wv.z); acc.w += v * bf2f(wv.w);
        }
    } else {
#pragma unroll 4
        for (int j = 0; j < TK; j++) {
            float v = sv[j];
            float4 wv = ((const float4*)(Wd + (size_t)si[j] * DD))[t];
            acc.x += v * wv.x; acc.y += v * wv.y;
            acc.z += v * wv.z; acc.w += v * wv.w;
        }
    }
    ((float4*)out)[(size_t)b * (DD / 4) + t] = acc;
}

extern "C" void kernel_launch(void* const* d_in, const int* in_sizes, int n_in,
                              void* d_out, int out_size, void* d_ws, size_t ws_size,
                              hipStream_t stream) {
    const float* x  = (const float*)d_in[0];
    const float* pb = (const float*)d_in[1];
    const float* We = (const float*)d_in[2];
    const float* lb = (const float*)d_in[3];
    const float* Wd = (const float*)d_in[4];
    float* out = (float*)d_out;
    char* ws = (char*)d_ws;
    (void)in_sizes; (void)n_in; (void)out_size;

    const size_t SZ_AP   = (size_t)NB * DD;                  // 6.3 MB (fp8)
    const size_t SZ_BP   = (size_t)FF * DD;                  // 25.2 MB (fp8)
    const size_t SZ_WT32 = (size_t)FF * DD * 4;              // 100.7 MB
    const size_t SZ_WD16 = (size_t)FF * DD * 2;              // 50.3 MB
    const size_t SZ_CAND = (size_t)NB * NSEG * SLOT * 4;     // 67.1 MB (NOT memset)
    const size_t SZ_CC8  = (size_t)NB * NSEG;                // 2.1 MB (fully written by gemm)
    const size_t SZ_TAU  = (size_t)NB * 4;
    const size_t SZ_RIDX = (size_t)NB * RUNC * 4;
    const size_t SZ_RCNT = (size_t)NB * 4;
    const size_t SZ_SIDX = (size_t)NB * TK * 4;
    const size_t SZ_SVAL = (size_t)NB * TK * 4;

    size_t need_base = SZ_AP + SZ_BP + SZ_CAND + SZ_CC8 + (size_t)NB * 8 + NS2 * 4 +
                       SZ_TAU + SZ_RIDX + SZ_RCNT + SZ_SIDX + SZ_SVAL;
    int use_t = (ws_size >= need_base + SZ_WT32 + SZ_WD16) ? 1 : 0;

    size_t off = 0;
    uchar* Ap     = (uchar*)(ws + off); off += SZ_AP;
    uchar* Bp     = (uchar*)(ws + off); off += SZ_BP;
    float* Wt32   = nullptr;
    ushort* Wd16  = nullptr;
    if (use_t) {
        Wt32 = (float*)(ws + off); off += SZ_WT32;
        Wd16 = (ushort*)(ws + off); off += SZ_WD16;
    }
    char* ctrl0   = (char*)(ws + off);                       // memset region: rowbad + s2part
    unsigned* rowbad = (unsigned*)(ws + off); off += (size_t)NB * 4;
    float* s2part = (float*)(ws + off); off += NS2 * 4;
    size_t ctrl_bytes = (size_t)((ws + off) - ctrl0);
    unsigned* cand = (unsigned*)(ws + off); off += SZ_CAND;
    uchar* ccnt8  = (uchar*)(ws + off); off += SZ_CC8;
    unsigned* flagv = (unsigned*)(ws + off); off += (size_t)NB * 4;
    float* tau    = (float*)(ws + off); off += SZ_TAU;
    int* ridx     = (int*)(ws + off); off += SZ_RIDX;
    int* rcnt     = (int*)(ws + off); off += SZ_RCNT;
    int* sidx     = (int*)(ws + off); off += SZ_SIDX;
    float* sval   = (float*)(ws + off); off += SZ_SVAL;

    hipMemsetAsync(ctrl0, 0, ctrl_bytes, stream);
    prep_x_k<<<2048, 256, 0, stream>>>(x, pb, Ap);
    prep_w_k<<<dim3(FF / 32, DD / 32), 256, 0, stream>>>(We, Bp, Wt32, s2part);
    if (use_t) prep_wd_k<<<2048, 256, 0, stream>>>(Wd, Wd16);
    rn_k<<<NB / 4, 256, 0, stream>>>(x, pb, s2part, tau);
    gemm_k<<<(NB / 128) * (FF / 128), 256, 0, stream>>>(Ap, Bp, lb, tau, cand, ccnt8, rowbad);
    select2_k<<<NB, 256, 0, stream>>>(cand, ccnt8, rowbad, flagv, ridx, rcnt);
    fb_k<<<NB, 256, 0, stream>>>(flagv, x, pb, Bp, lb, ridx, rcnt);
    refine_k<<<NB, 256, 0, stream>>>(x, pb, We, Wt32, lb, ridx, rcnt, use_t, sidx, sval);
    decode_k<<<NB, 192, 0, stream>>>(sval, sidx, Wd16, Wd, pb, out);
}